// Round 9
// baseline (259.581 us; speedup 1.0000x reference)
//
#include <hip/hip_runtime.h>
#include <hip/hip_bf16.h>
#include <stdint.h>

#define M_DIM 8192
#define K_DIM 4096
#define N_DIM 4096

#define BM 256
#define BN 256
#define BKB 128             // K-bytes (=i8 elems) per tile
#define NT (K_DIM / BKB)    // 32 K-tiles
#define ATILE (BM * BKB)    // 32768 B
#define TBYTES (2 * ATILE)  // 65536 B per K-tile buffer (A half | B half)

typedef int i32x4 __attribute__((ext_vector_type(4)));

// ---------------------------------------------------------------------------
// Kernel 1: per-tensor activation quantization f32 -> i8 (unchanged, passing)
// ---------------------------------------------------------------------------
__global__ __launch_bounds__(256) void quant_x_kernel(
    const float* __restrict__ x, const float* __restrict__ scale_p,
    const int* __restrict__ off_p, int8_t* __restrict__ xq)
{
    const float s = scale_p[0];
    const float off = (float)off_p[0];
    long base = ((long)blockIdx.x * 256 + threadIdx.x) * 16;
    const float4* xin = (const float4*)(x + base);
    float v[16];
    *(float4*)(v + 0)  = xin[0];
    *(float4*)(v + 4)  = xin[1];
    *(float4*)(v + 8)  = xin[2];
    *(float4*)(v + 12) = xin[3];
    uint32_t pk[4];
#pragma unroll
    for (int g = 0; g < 4; ++g) {
        uint32_t p = 0;
#pragma unroll
        for (int j = 0; j < 4; ++j) {
            float q = rintf(v[g * 4 + j] / s) + off;
            q = fminf(fmaxf(q, -128.0f), 127.0f);
            int qi = (int)q;
            p |= ((uint32_t)(qi & 0xff)) << (8 * j);
        }
        pk[g] = p;
    }
    uint4 o; o.x = pk[0]; o.y = pk[1]; o.z = pk[2]; o.w = pk[3];
    *(uint4*)(xq + base) = o;
}

// ---------------------------------------------------------------------------
// Kernel 2: weight pack + permutation fold (unchanged, passing)
// ---------------------------------------------------------------------------
__global__ __launch_bounds__(256) void pack_w_kernel(
    const int* __restrict__ w, const int* __restrict__ index,
    const float* __restrict__ deq, const int* __restrict__ qb,
    int8_t* __restrict__ bp, float* __restrict__ dsp, int* __restrict__ qbp)
{
    int j = blockIdx.x;
    int t = threadIdx.x;
    int src = index[j];
    const int4* wrow = (const int4*)(w + (long)src * K_DIM);
    uint32_t pk[4];
#pragma unroll
    for (int g = 0; g < 4; ++g) {
        int4 c = wrow[t * 4 + g];
        pk[g] = ((uint32_t)(c.x & 0xff)) | (((uint32_t)(c.y & 0xff)) << 8) |
                (((uint32_t)(c.z & 0xff)) << 16) | (((uint32_t)(c.w & 0xff)) << 24);
    }
    uint4 o; o.x = pk[0]; o.y = pk[1]; o.z = pk[2]; o.w = pk[3];
    *(uint4*)(bp + (long)j * K_DIM + t * 16) = o;
    if (t == 0) { dsp[j] = deq[src]; qbp[j] = qb[src]; }
}

// ---------------------------------------------------------------------------
// Kernel 3: 256x256 int8 GEMM, 4 waves x 128x128 wave-tile, BKB=128, LDS
// double-buffer (2 x 64KB). Design: minimize DS bytes/MAC (0.0156 B/MAC,
// -33% vs 128x64 wave tile) and amortize tile-boundary overhead over 2x
// MFMA. 1 wave/SIMD; overlap is in-wave: compiler emits counted lgkmcnt
// between ds_read_b128 and dependent MFMAs (m97-verified), so the 32
// frag reads pipeline under the 128-MFMA stream. acc[8][8] (256 regs)
// lives in AGPRs (unified file, ~420 total < 512).
// Per tile t: {16 ds_read kk0 -> 64 MFMA kk0 -> 16 ds_read kk1 ->
// 16 global_load_lds of t+1 into other buffer -> 64 MFMA kk1} ->
// lgkmcnt(0) -> vmcnt(0) (loads issued ~1300cyc earlier: near-free) ->
// s_barrier. Swizzle: 8 slots/row, phys = s ^ (row&7) (R1-verified,
// 0 bank conflicts); kk1 offsets = kk0 ^ 64.
// ---------------------------------------------------------------------------
__device__ __forceinline__ void gload_lds16(const int8_t* g, int8_t* l)
{
    __builtin_amdgcn_global_load_lds(
        (const __attribute__((address_space(1))) uint32_t*)g,
        (__attribute__((address_space(3))) uint32_t*)l, 16, 0, 0);
}

__global__ __launch_bounds__(256, 1) void gemm_i8_kernel(
    const int8_t* __restrict__ A, const int8_t* __restrict__ B,
    const float* __restrict__ dsp, const int* __restrict__ qbp,
    float* __restrict__ C)
{
    __shared__ int8_t tb0[TBYTES];   // buffer 0 (A 32KB | B 32KB)
    __shared__ int8_t tb1[TBYTES];   // buffer 1      -> 128 KB total

    // XCD-aware bijective swizzle (grid = 512, divisible by 8)
    int bid = blockIdx.x;
    int swz = (bid & 7) * (gridDim.x >> 3) + (bid >> 3);
    int bm = swz & 31;              // M/BM = 32
    int bn = swz >> 5;              // N/BN = 16
    int brow = bm * BM, bcol = bn * BN;

    int t = threadIdx.x;
    int wv = t >> 6;                // 4 waves (2M x 2N)
    int l  = t & 63;
    int lr = l & 15;                // row within 16x16 fragment
    int ls = l >> 4;                // logical 16B k-slot within kk-half
    int wrM = (wv >> 1) * 128;      // wave row offset
    int wcN = (wv & 1) * 128;       // wave col offset
    int p0 = ls ^ (lr & 7);         // swizzled phys slot, kk=0 (lane-const)

    // Fragment base byte offsets (kk=0); kk=1 offsets are base ^ 64.
    const int aL0 = (wrM + lr) * BKB + p0 * 16;
    const int bL0 = ATILE + (wcN + lr) * BKB + p0 * 16;
    const int aL1 = aL0 ^ 64;
    const int bL1 = bL0 ^ 64;

    // Staging lane geometry: chunk ca = i*256 + t at LDS byte ca*16;
    // row(ca) = i*32 + (t>>3); phys slot = t&7 holds logical
    // lg = (t&7) ^ (row&7) = (t&7) ^ ((t>>3)&7)  (i-independent).
    int rowl = t >> 3;
    int lg = (t & 7) ^ (rowl & 7);
    const int8_t* sA = A + (long)(brow + rowl) * K_DIM + lg * 16;
    const int8_t* sB = B + (long)(bcol + rowl) * K_DIM + lg * 16;
    const int dal = t * 16;

#define STAGE16(STG) do { \
        _Pragma("unroll") \
        for (int i = 0; i < 8; ++i) \
            gload_lds16(sA + (long)i * (32 * K_DIM), (STG) + i * 4096 + dal); \
        _Pragma("unroll") \
        for (int i = 0; i < 8; ++i) \
            gload_lds16(sB + (long)i * (32 * K_DIM), (STG) + ATILE + i * 4096 + dal); \
        sA += BKB; sB += BKB; \
    } while (0)

// One K-tile: frag reads kk0 -> MFMA kk0 -> frag reads kk1 -> stage t+1 ->
// MFMA kk1 -> (tile end sync unless LAST).
#define TILE(CUR, STG, DO_STAGE, LAST) do { \
        i32x4 af[8], bf[8], af2[8], bf2[8]; \
        _Pragma("unroll") \
        for (int n = 0; n < 8; ++n) bf[n] = *(const i32x4*)((CUR) + bL0 + n * 2048); \
        _Pragma("unroll") \
        for (int m = 0; m < 8; ++m) af[m] = *(const i32x4*)((CUR) + aL0 + m * 2048); \
        _Pragma("unroll") \
        for (int m = 0; m < 8; ++m) \
        _Pragma("unroll") \
        for (int n = 0; n < 8; ++n) \
            acc[m][n] = __builtin_amdgcn_mfma_i32_16x16x64_i8( \
                af[m], bf[n], acc[m][n], 0, 0, 0); \
        _Pragma("unroll") \
        for (int n = 0; n < 8; ++n) bf2[n] = *(const i32x4*)((CUR) + bL1 + n * 2048); \
        _Pragma("unroll") \
        for (int m = 0; m < 8; ++m) af2[m] = *(const i32x4*)((CUR) + aL1 + m * 2048); \
        if (DO_STAGE) STAGE16(STG); \
        _Pragma("unroll") \
        for (int m = 0; m < 8; ++m) \
        _Pragma("unroll") \
        for (int n = 0; n < 8; ++n) \
            acc[m][n] = __builtin_amdgcn_mfma_i32_16x16x64_i8( \
                af2[m], bf2[n], acc[m][n], 0, 0, 0); \
        if (!(LAST)) { \
            asm volatile("s_waitcnt lgkmcnt(0)" ::: "memory"); \
            asm volatile("s_waitcnt vmcnt(0)" ::: "memory"); \
            __builtin_amdgcn_s_barrier(); \
        } \
    } while (0)

    // Prologue: stage tile 0 -> tb0
    STAGE16(tb0);
    asm volatile("s_waitcnt vmcnt(0)" ::: "memory");
    __builtin_amdgcn_s_barrier();

    i32x4 acc[8][8] = {};

    // Main loop: kt = 0..29 (15 x 2), then kt=30 (stages 31), kt=31 (last).
    for (int it = 0; it < 15; ++it) {
        TILE(tb0, tb1, true, false);    // even kt: read tb0, stage -> tb1
        TILE(tb1, tb0, true, false);    // odd  kt: read tb1, stage -> tb0
    }
    TILE(tb0, tb1, true, false);        // kt = 30
    TILE(tb1, tb0, false, true);        // kt = 31 (no stage, no end sync)

#undef STAGE16
#undef TILE

    // Epilogue: C/D layout col = lane&15, row = (lane>>4)*4 + reg
#pragma unroll
    for (int n = 0; n < 8; ++n) {
        int gc = bcol + wcN + n * 16 + lr;
        float ds = dsp[gc];
        int qb = qbp[gc];
#pragma unroll
        for (int m = 0; m < 8; ++m) {
            int gr0 = brow + wrM + m * 16 + ls * 4;
#pragma unroll
            for (int r = 0; r < 4; ++r) {
                C[(long)(gr0 + r) * N_DIM + gc] = (float)(acc[m][n][r] + qb) * ds;
            }
        }
    }
}

// ---------------------------------------------------------------------------
extern "C" void kernel_launch(void* const* d_in, const int* in_sizes, int n_in,
                              void* d_out, int out_size, void* d_ws, size_t ws_size,
                              hipStream_t stream)
{
    (void)in_sizes; (void)n_in; (void)out_size; (void)ws_size;
    const float* x   = (const float*)d_in[0];
    const int*   w   = (const int*)d_in[1];
    const float* is  = (const float*)d_in[2];
    const int*   io  = (const int*)d_in[3];
    const float* dq  = (const float*)d_in[4];
    const int*   qb  = (const int*)d_in[5];
    const int*   idx = (const int*)d_in[6];
    float* out = (float*)d_out;

    int8_t* xq  = (int8_t*)d_ws;                           // 33554432 B
    int8_t* bp  = xq + (size_t)M_DIM * K_DIM;              // 16777216 B
    float*  dsp = (float*)(bp + (size_t)N_DIM * K_DIM);    // 16384 B
    int*    qbp = (int*)(dsp + N_DIM);                     // 16384 B

    long quant_blocks = ((long)M_DIM * K_DIM) / 16 / 256;  // 8192
    quant_x_kernel<<<(int)quant_blocks, 256, 0, stream>>>(x, is, io, xq);
    pack_w_kernel<<<N_DIM, 256, 0, stream>>>(w, idx, dq, qb, bp, dsp, qbp);
    gemm_i8_kernel<<<(M_DIM / BM) * (N_DIM / BN), 256, 0, stream>>>(xq, bp, dsp, qbp, out);
}

// Round 10
// 214.904 us; speedup vs baseline: 1.2079x; 1.2079x over previous
//
#include <hip/hip_runtime.h>
#include <hip/hip_bf16.h>
#include <stdint.h>

#define M_DIM 8192
#define K_DIM 4096
#define N_DIM 4096

#define BM 256
#define BN 256
#define BKB 64              // K-bytes (=i8 elems) per tile
#define NT (K_DIM / BKB)    // 64 K-tiles
#define ATILE (BM * BKB)    // 16384 B
#define TBYTES (ATILE + BN * BKB)   // 32768 B per K-tile buffer

typedef int i32x4 __attribute__((ext_vector_type(4)));

// ---------------------------------------------------------------------------
// Kernel 1: per-tensor activation quantization f32 -> i8 (unchanged, passing)
// ---------------------------------------------------------------------------
__global__ __launch_bounds__(256) void quant_x_kernel(
    const float* __restrict__ x, const float* __restrict__ scale_p,
    const int* __restrict__ off_p, int8_t* __restrict__ xq)
{
    const float s = scale_p[0];
    const float off = (float)off_p[0];
    long base = ((long)blockIdx.x * 256 + threadIdx.x) * 16;
    const float4* xin = (const float4*)(x + base);
    float v[16];
    *(float4*)(v + 0)  = xin[0];
    *(float4*)(v + 4)  = xin[1];
    *(float4*)(v + 8)  = xin[2];
    *(float4*)(v + 12) = xin[3];
    uint32_t pk[4];
#pragma unroll
    for (int g = 0; g < 4; ++g) {
        uint32_t p = 0;
#pragma unroll
        for (int j = 0; j < 4; ++j) {
            float q = rintf(v[g * 4 + j] / s) + off;
            q = fminf(fmaxf(q, -128.0f), 127.0f);
            int qi = (int)q;
            p |= ((uint32_t)(qi & 0xff)) << (8 * j);
        }
        pk[g] = p;
    }
    uint4 o; o.x = pk[0]; o.y = pk[1]; o.z = pk[2]; o.w = pk[3];
    *(uint4*)(xq + base) = o;
}

// ---------------------------------------------------------------------------
// Kernel 2: weight pack + permutation fold (unchanged, passing)
// ---------------------------------------------------------------------------
__global__ __launch_bounds__(256) void pack_w_kernel(
    const int* __restrict__ w, const int* __restrict__ index,
    const float* __restrict__ deq, const int* __restrict__ qb,
    int8_t* __restrict__ bp, float* __restrict__ dsp, int* __restrict__ qbp)
{
    int j = blockIdx.x;
    int t = threadIdx.x;
    int src = index[j];
    const int4* wrow = (const int4*)(w + (long)src * K_DIM);
    uint32_t pk[4];
#pragma unroll
    for (int g = 0; g < 4; ++g) {
        int4 c = wrow[t * 4 + g];
        pk[g] = ((uint32_t)(c.x & 0xff)) | (((uint32_t)(c.y & 0xff)) << 8) |
                (((uint32_t)(c.z & 0xff)) << 16) | (((uint32_t)(c.w & 0xff)) << 24);
    }
    uint4 o; o.x = pk[0]; o.y = pk[1]; o.z = pk[2]; o.w = pk[3];
    *(uint4*)(bp + (long)j * K_DIM + t * 16) = o;
    if (t == 0) { dsp[j] = deq[src]; qbp[j] = qb[src]; }
}

// ---------------------------------------------------------------------------
// Kernel 3: 256x256 int8 GEMM. Register read-ahead (R4) + CHUNKED program-
// order interleave (new): per K-tile, 4 chunks of {1 gload_lds(t+3) ||
// 3 ds_read(t+1 -> W frag set) -> sched_barrier(0) -> 8 MFMA(R frag set) ->
// sched_barrier(0)}, then vmcnt(4) + s_barrier.
// Mechanism: waves issue in order; a contiguous 12-read block under fair
// DS arbitration makes ALL waves finish read-issue simultaneously -> CU-wide
// DS burst then MFMA burst (the additive behavior of R2-R9). Spreading the
// reads 3:8 through the MFMA stream keeps the matrix pipe fed while DS
// requests trickle. MFMAs use last tile's frag set -> compiler emits a
// counted lgkmcnt(3) (instantly satisfied), never a drain.
// Ring-4 LDS, stage distance 3, R4's verified safety invariants.
// ---------------------------------------------------------------------------
__device__ __forceinline__ void gload_lds16(const int8_t* g, int8_t* l)
{
    __builtin_amdgcn_global_load_lds(
        (const __attribute__((address_space(1))) uint32_t*)g,
        (__attribute__((address_space(3))) uint32_t*)l, 16, 0, 0);
}

__global__ __launch_bounds__(512, 2) void gemm_i8_kernel(
    const int8_t* __restrict__ A, const int8_t* __restrict__ B,
    const float* __restrict__ dsp, const int* __restrict__ qbp,
    float* __restrict__ C)
{
    __shared__ int8_t tb0[TBYTES];
    __shared__ int8_t tb1[TBYTES];
    __shared__ int8_t tb2[TBYTES];
    __shared__ int8_t tb3[TBYTES];   // 128 KB total

    // XCD-aware bijective swizzle (grid = 512, divisible by 8)
    int bid = blockIdx.x;
    int swz = (bid & 7) * (gridDim.x >> 3) + (bid >> 3);
    int bm = swz & 31;              // M/BM = 32
    int bn = swz >> 5;              // N/BN = 16
    int brow = bm * BM, bcol = bn * BN;

    int t = threadIdx.x;
    int wv = t >> 6;
    int l  = t & 63;
    int lr = l & 15;                // row within 16x16 fragment
    int ls = l >> 4;                // logical 16B k-slot
    int wrM = (wv >> 2) * 128;      // wave row offset (2 M-waves)
    int wcN = (wv & 3) * 64;        // wave col offset (4 N-waves)
    int pslot = ls ^ ((lr >> 1) & 3);   // swizzled physical slot (lane-const)

    // ds_read byte offsets within a K-tile buffer (A half then B half)
    int aoff[8], boff[4];
#pragma unroll
    for (int m = 0; m < 8; ++m)
        aoff[m] = (wrM + m * 16 + lr) * BKB + pslot * 16;
#pragma unroll
    for (int n = 0; n < 4; ++n)
        boff[n] = ATILE + (wcN + n * 16 + lr) * BKB + pslot * 16;

    // Staging: 2 A-chunks + 2 B-chunks (16B each) per thread per K-tile.
    // Linear LDS dest; global source pre-swizzled (slot = (ca&3)^((row>>1)&3)).
    int ca0 = t, ca1 = 512 + t;
    int r0 = ca0 >> 2, r1 = ca1 >> 2;
    const int8_t* sa0 = A + (long)(brow + r0) * K_DIM + ((ca0 & 3) ^ ((r0 >> 1) & 3)) * 16;
    const int8_t* sa1 = A + (long)(brow + r1) * K_DIM + ((ca1 & 3) ^ ((r1 >> 1) & 3)) * 16;
    const int8_t* sb0 = B + (long)(bcol + r0) * K_DIM + ((ca0 & 3) ^ ((r0 >> 1) & 3)) * 16;
    const int8_t* sb1 = B + (long)(bcol + r1) * K_DIM + ((ca1 & 3) ^ ((r1 >> 1) & 3)) * 16;
    const int da0 = ca0 * 16, da1 = ca1 * 16;
    const int db0 = ATILE + ca0 * 16, db1 = ATILE + ca1 * 16;

    i32x4 afA[8], bfA[4], afB[8], bfB[4];
    i32x4 acc[8][4] = {};

// 2 M-rows of the R set against all 4 B frags (8 MFMAs)
#define MF2(AFR, BFR, M0) do { \
        _Pragma("unroll") \
        for (int mm = 0; mm < 2; ++mm) \
        _Pragma("unroll") \
        for (int nn = 0; nn < 4; ++nn) \
            acc[(M0) + mm][nn] = __builtin_amdgcn_mfma_i32_16x16x64_i8( \
                AFR[(M0) + mm], BFR[nn], acc[(M0) + mm][nn], 0, 0, 0); \
    } while (0)

#define SB0() __builtin_amdgcn_sched_barrier(0)

// One K-tile: compute on R set, fill W set from RD buffer, stage t+3 into
// STG buffer (1 gload per chunk), 3 reads : 8 MFMAs per chunk.
#define TILE(AFR, BFR, AFW, BFW, RD, STG, DO_ST, VMC) do { \
        /* chunk 0 */ \
        if (DO_ST) { gload_lds16(sa0, (STG) + da0); sa0 += BKB; } \
        BFW[0] = *(const i32x4*)((RD) + boff[0]); \
        BFW[1] = *(const i32x4*)((RD) + boff[1]); \
        BFW[2] = *(const i32x4*)((RD) + boff[2]); \
        SB0(); __builtin_amdgcn_s_setprio(1); \
        MF2(AFR, BFR, 0); \
        __builtin_amdgcn_s_setprio(0); SB0(); \
        /* chunk 1 */ \
        if (DO_ST) { gload_lds16(sa1, (STG) + da1); sa1 += BKB; } \
        BFW[3] = *(const i32x4*)((RD) + boff[3]); \
        AFW[0] = *(const i32x4*)((RD) + aoff[0]); \
        AFW[1] = *(const i32x4*)((RD) + aoff[1]); \
        SB0(); __builtin_amdgcn_s_setprio(1); \
        MF2(AFR, BFR, 2); \
        __builtin_amdgcn_s_setprio(0); SB0(); \
        /* chunk 2 */ \
        if (DO_ST) { gload_lds16(sb0, (STG) + db0); sb0 += BKB; } \
        AFW[2] = *(const i32x4*)((RD) + aoff[2]); \
        AFW[3] = *(const i32x4*)((RD) + aoff[3]); \
        AFW[4] = *(const i32x4*)((RD) + aoff[4]); \
        SB0(); __builtin_amdgcn_s_setprio(1); \
        MF2(AFR, BFR, 4); \
        __builtin_amdgcn_s_setprio(0); SB0(); \
        /* chunk 3 */ \
        if (DO_ST) { gload_lds16(sb1, (STG) + db1); sb1 += BKB; } \
        AFW[5] = *(const i32x4*)((RD) + aoff[5]); \
        AFW[6] = *(const i32x4*)((RD) + aoff[6]); \
        AFW[7] = *(const i32x4*)((RD) + aoff[7]); \
        SB0(); __builtin_amdgcn_s_setprio(1); \
        MF2(AFR, BFR, 6); \
        __builtin_amdgcn_s_setprio(0); SB0(); \
        asm volatile("s_waitcnt vmcnt(" #VMC ")" ::: "memory"); \
        __builtin_amdgcn_s_barrier(); \
    } while (0)

#define STAGE4(STG) do { \
        gload_lds16(sa0, (STG) + da0); \
        gload_lds16(sa1, (STG) + da1); \
        gload_lds16(sb0, (STG) + db0); \
        gload_lds16(sb1, (STG) + db1); \
        sa0 += BKB; sa1 += BKB; sb0 += BKB; sb1 += BKB; \
    } while (0)

    // Prologue: stage tiles 0,1,2 -> buffers 0,1,2
    STAGE4(tb0); STAGE4(tb1); STAGE4(tb2);
    asm volatile("s_waitcnt vmcnt(4)" ::: "memory");   // tiles 0,1 resident
    __builtin_amdgcn_s_barrier();

    // Read tile 0 fragments -> set A (one-time contiguous read)
#pragma unroll
    for (int n = 0; n < 4; ++n) bfA[n] = *(const i32x4*)(tb0 + boff[n]);
#pragma unroll
    for (int m = 0; m < 8; ++m) afA[m] = *(const i32x4*)(tb0 + aoff[m]);

    // Main loop: kt = 0..59 (15 x ring period 4)
    for (int it = 0; it < 15; ++it) {
        TILE(afA, bfA, afB, bfB, tb1, tb3, true, 4);   // kt%4==0
        TILE(afB, bfB, afA, bfA, tb2, tb0, true, 4);   // kt%4==1
        TILE(afA, bfA, afB, bfB, tb3, tb1, true, 4);   // kt%4==2
        TILE(afB, bfB, afA, bfA, tb0, tb2, true, 4);   // kt%4==3
    }
    // kt=60: compute A(60), fill B(61 from tb1), stage 63 -> tb3
    TILE(afA, bfA, afB, bfB, tb1, tb3, true, 4);
    // kt=61: compute B(61), fill A(62 from tb2), no stage; drain all loads
    TILE(afB, bfB, afA, bfA, tb2, tb0, false, 0);
    // kt=62: compute A(62), fill B(63 from tb3) — simple serial tail
    {
#pragma unroll
        for (int n = 0; n < 4; ++n) bfB[n] = *(const i32x4*)(tb3 + boff[n]);
#pragma unroll
        for (int m = 0; m < 8; ++m) afB[m] = *(const i32x4*)(tb3 + aoff[m]);
#pragma unroll
        for (int m = 0; m < 8; ++m)
#pragma unroll
            for (int n = 0; n < 4; ++n)
                acc[m][n] = __builtin_amdgcn_mfma_i32_16x16x64_i8(
                    afA[m], bfA[n], acc[m][n], 0, 0, 0);
    }
    // kt=63: compute B(63)
#pragma unroll
    for (int m = 0; m < 8; ++m)
#pragma unroll
        for (int n = 0; n < 4; ++n)
            acc[m][n] = __builtin_amdgcn_mfma_i32_16x16x64_i8(
                afB[m], bfB[n], acc[m][n], 0, 0, 0);

#undef TILE
#undef STAGE4
#undef MF2
#undef SB0

    // Epilogue: C/D layout col = lane&15, row = (lane>>4)*4 + reg
#pragma unroll
    for (int n = 0; n < 4; ++n) {
        int gc = bcol + wcN + n * 16 + lr;
        float ds = dsp[gc];
        int qb = qbp[gc];
#pragma unroll
        for (int m = 0; m < 8; ++m) {
            int gr0 = brow + wrM + m * 16 + ls * 4;
#pragma unroll
            for (int r = 0; r < 4; ++r) {
                C[(long)(gr0 + r) * N_DIM + gc] = (float)(acc[m][n][r] + qb) * ds;
            }
        }
    }
}

// ---------------------------------------------------------------------------
extern "C" void kernel_launch(void* const* d_in, const int* in_sizes, int n_in,
                              void* d_out, int out_size, void* d_ws, size_t ws_size,
                              hipStream_t stream)
{
    (void)in_sizes; (void)n_in; (void)out_size; (void)ws_size;
    const float* x   = (const float*)d_in[0];
    const int*   w   = (const int*)d_in[1];
    const float* is  = (const float*)d_in[2];
    const int*   io  = (const int*)d_in[3];
    const float* dq  = (const float*)d_in[4];
    const int*   qb  = (const int*)d_in[5];
    const int*   idx = (const int*)d_in[6];
    float* out = (float*)d_out;

    int8_t* xq  = (int8_t*)d_ws;                           // 33554432 B
    int8_t* bp  = xq + (size_t)M_DIM * K_DIM;              // 16777216 B
    float*  dsp = (float*)(bp + (size_t)N_DIM * K_DIM);    // 16384 B
    int*    qbp = (int*)(dsp + N_DIM);                     // 16384 B

    long quant_blocks = ((long)M_DIM * K_DIM) / 16 / 256;  // 8192
    quant_x_kernel<<<(int)quant_blocks, 256, 0, stream>>>(x, is, io, xq);
    pack_w_kernel<<<N_DIM, 256, 0, stream>>>(w, idx, dq, qb, bp, dsp, qbp);
    gemm_i8_kernel<<<(M_DIM / BM) * (N_DIM / BN), 512, 0, stream>>>(xq, bp, dsp, qbp, out);
}

// Round 11
// 198.010 us; speedup vs baseline: 1.3109x; 1.0853x over previous
//
#include <hip/hip_runtime.h>
#include <hip/hip_bf16.h>
#include <stdint.h>

#define M_DIM 8192
#define K_DIM 4096
#define N_DIM 4096

#define BM 256
#define BN 256
#define BKB 64              // K-bytes (=i8 elems) per tile
#define NT (K_DIM / BKB)    // 64 K-tiles
#define ATILE (BM * BKB)    // 16384 B
#define TBYTES (ATILE + BN * BKB)   // 32768 B per K-tile buffer

typedef int i32x4  __attribute__((ext_vector_type(4)));
typedef int i32x16 __attribute__((ext_vector_type(16)));

// ---------------------------------------------------------------------------
// Kernel 1: per-tensor activation quantization f32 -> i8 (unchanged, passing)
// ---------------------------------------------------------------------------
__global__ __launch_bounds__(256) void quant_x_kernel(
    const float* __restrict__ x, const float* __restrict__ scale_p,
    const int* __restrict__ off_p, int8_t* __restrict__ xq)
{
    const float s = scale_p[0];
    const float off = (float)off_p[0];
    long base = ((long)blockIdx.x * 256 + threadIdx.x) * 16;
    const float4* xin = (const float4*)(x + base);
    float v[16];
    *(float4*)(v + 0)  = xin[0];
    *(float4*)(v + 4)  = xin[1];
    *(float4*)(v + 8)  = xin[2];
    *(float4*)(v + 12) = xin[3];
    uint32_t pk[4];
#pragma unroll
    for (int g = 0; g < 4; ++g) {
        uint32_t p = 0;
#pragma unroll
        for (int j = 0; j < 4; ++j) {
            float q = rintf(v[g * 4 + j] / s) + off;
            q = fminf(fmaxf(q, -128.0f), 127.0f);
            int qi = (int)q;
            p |= ((uint32_t)(qi & 0xff)) << (8 * j);
        }
        pk[g] = p;
    }
    uint4 o; o.x = pk[0]; o.y = pk[1]; o.z = pk[2]; o.w = pk[3];
    *(uint4*)(xq + base) = o;
}

// ---------------------------------------------------------------------------
// Kernel 2: weight pack + permutation fold (unchanged, passing)
// ---------------------------------------------------------------------------
__global__ __launch_bounds__(256) void pack_w_kernel(
    const int* __restrict__ w, const int* __restrict__ index,
    const float* __restrict__ deq, const int* __restrict__ qb,
    int8_t* __restrict__ bp, float* __restrict__ dsp, int* __restrict__ qbp)
{
    int j = blockIdx.x;
    int t = threadIdx.x;
    int src = index[j];
    const int4* wrow = (const int4*)(w + (long)src * K_DIM);
    uint32_t pk[4];
#pragma unroll
    for (int g = 0; g < 4; ++g) {
        int4 c = wrow[t * 4 + g];
        pk[g] = ((uint32_t)(c.x & 0xff)) | (((uint32_t)(c.y & 0xff)) << 8) |
                (((uint32_t)(c.z & 0xff)) << 16) | (((uint32_t)(c.w & 0xff)) << 24);
    }
    uint4 o; o.x = pk[0]; o.y = pk[1]; o.z = pk[2]; o.w = pk[3];
    *(uint4*)(bp + (long)j * K_DIM + t * 16) = o;
    if (t == 0) { dsp[j] = deq[src]; qbp[j] = qb[src]; }
}

// ---------------------------------------------------------------------------
// Kernel 3: 256x256 int8 GEMM, R3/R7 additive-floor schedule, upgraded to
// v_mfma_i32_32x32x32_i8 (4404 vs 3944 TOPS ubench: -10% matrix-pipe time,
// identical LDS traffic). Per wave: 4x2 tiles of 32x32, 16 MFMA per K-tile.
// A/B frag: lane row r = l&31, k-half = l>>5; logical 16B slot s = kk*2+kh;
// phys = s ^ ((r>>1)&3) (same involution as staging -> verified pairing).
// C/D layout (m74/m101): col = lane&31, row = (reg&3) + 8*(reg>>2) +
// 4*(lane>>5). XCD swizzle inverted to A-residency: each XCD owns 4
// bm-panels (4MB A, L2-resident) and streams B.
// ---------------------------------------------------------------------------
__device__ __forceinline__ void gload_lds16(const int8_t* g, int8_t* l)
{
    __builtin_amdgcn_global_load_lds(
        (const __attribute__((address_space(1))) uint32_t*)g,
        (__attribute__((address_space(3))) uint32_t*)l, 16, 0, 0);
}

__global__ __launch_bounds__(512, 2) void gemm_i8_kernel(
    const int8_t* __restrict__ A, const int8_t* __restrict__ B,
    const float* __restrict__ dsp, const int* __restrict__ qbp,
    float* __restrict__ C)
{
    __shared__ int8_t tb0[TBYTES];
    __shared__ int8_t tb1[TBYTES];
    __shared__ int8_t tb2[TBYTES];   // 96 KB total

    // XCD-aware bijective swizzle (grid = 512): A-panel residency.
    // XCD x gets swz in [64x, 64x+64) -> bm in [4x,4x+4) (4MB of A, fits
    // the 4MB XCD L2), sweeping all 16 bn while A stays hot.
    int bid = blockIdx.x;
    int swz = (bid & 7) * (gridDim.x >> 3) + (bid >> 3);
    int bn = swz & 15;              // N/BN = 16
    int bm = swz >> 4;              // M/BM = 32
    int brow = bm * BM, bcol = bn * BN;

    int t = threadIdx.x;
    int wv = t >> 6;
    int l  = t & 63;
    int r32 = l & 31;               // row within 32x32 fragment
    int kh  = l >> 5;               // k-half (16B) within K=32 slice
    int wrM = (wv >> 2) * 128;      // wave row offset (2 M-waves)
    int wcN = (wv & 3) * 64;        // wave col offset (4 N-waves)
    int sxor = (r32 >> 1) & 3;      // swizzle term (lane-const)

    // ds_read byte offsets: aoff[m][kk], boff[n][kk]
    int aoff[4][2], boff[2][2];
#pragma unroll
    for (int m = 0; m < 4; ++m)
#pragma unroll
        for (int kk = 0; kk < 2; ++kk) {
            int s = kk * 2 + kh;
            aoff[m][kk] = (wrM + m * 32 + r32) * BKB + (s ^ sxor) * 16;
        }
#pragma unroll
    for (int n = 0; n < 2; ++n)
#pragma unroll
        for (int kk = 0; kk < 2; ++kk) {
            int s = kk * 2 + kh;
            boff[n][kk] = ATILE + (wcN + n * 32 + r32) * BKB + (s ^ sxor) * 16;
        }

    // Staging: 2 A-chunks + 2 B-chunks (16B each) per thread per K-tile.
    // Linear LDS dest; global source pre-swizzled (slot = (ca&3)^((row>>1)&3)).
    int ca0 = t, ca1 = 512 + t;
    int r0 = ca0 >> 2, r1 = ca1 >> 2;
    const int8_t* sa0 = A + (long)(brow + r0) * K_DIM + ((ca0 & 3) ^ ((r0 >> 1) & 3)) * 16;
    const int8_t* sa1 = A + (long)(brow + r1) * K_DIM + ((ca1 & 3) ^ ((r1 >> 1) & 3)) * 16;
    const int8_t* sb0 = B + (long)(bcol + r0) * K_DIM + ((ca0 & 3) ^ ((r0 >> 1) & 3)) * 16;
    const int8_t* sb1 = B + (long)(bcol + r1) * K_DIM + ((ca1 & 3) ^ ((r1 >> 1) & 3)) * 16;
    const int da0 = ca0 * 16, da1 = ca1 * 16;
    const int db0 = ATILE + ca0 * 16, db1 = ATILE + ca1 * 16;

#define STAGE4(STG) do { \
        gload_lds16(sa0, (STG) + da0); \
        gload_lds16(sa1, (STG) + da1); \
        gload_lds16(sb0, (STG) + db0); \
        gload_lds16(sb1, (STG) + db1); \
        sa0 += BKB; sa1 += BKB; sb0 += BKB; sb1 += BKB; \
    } while (0)

// One K-tile (R3 order: frag reads -> stage -> MFMA -> lgkm0 -> vmcnt -> bar)
#define GEMM_TILE(CUR, STG, KT) do { \
        i32x4 af[4][2], bf[2][2]; \
        _Pragma("unroll") \
        for (int n = 0; n < 2; ++n) bf[n][0] = *(const i32x4*)((CUR) + boff[n][0]); \
        _Pragma("unroll") \
        for (int m = 0; m < 4; ++m) af[m][0] = *(const i32x4*)((CUR) + aoff[m][0]); \
        _Pragma("unroll") \
        for (int n = 0; n < 2; ++n) bf[n][1] = *(const i32x4*)((CUR) + boff[n][1]); \
        _Pragma("unroll") \
        for (int m = 0; m < 4; ++m) af[m][1] = *(const i32x4*)((CUR) + aoff[m][1]); \
        const bool _st = (KT) + 2 < NT; \
        if (_st) STAGE4(STG); \
        _Pragma("unroll") \
        for (int kk = 0; kk < 2; ++kk) \
        _Pragma("unroll") \
        for (int m = 0; m < 4; ++m) \
        _Pragma("unroll") \
        for (int n = 0; n < 2; ++n) \
            acc[m][n] = __builtin_amdgcn_mfma_i32_32x32x32_i8( \
                af[m][kk], bf[n][kk], acc[m][n], 0, 0, 0); \
        asm volatile("s_waitcnt lgkmcnt(0)" ::: "memory"); \
        if (_st) asm volatile("s_waitcnt vmcnt(4)" ::: "memory"); \
        else     asm volatile("s_waitcnt vmcnt(0)" ::: "memory"); \
        __builtin_amdgcn_s_barrier(); \
    } while (0)

    // Prologue: stage tiles 0 -> tb0, 1 -> tb1
    STAGE4(tb0);
    STAGE4(tb1);
    asm volatile("s_waitcnt vmcnt(4)" ::: "memory");   // tile 0 resident
    __builtin_amdgcn_s_barrier();

    i32x16 acc[4][2] = {};

    // Main loop: 63 tiles = 21 x ring period 3; tail tile 63 (63%3==0 -> tb0).
    for (int kt = 0; kt < 63; kt += 3) {
        GEMM_TILE(tb0, tb2, kt);
        GEMM_TILE(tb1, tb0, kt + 1);
        GEMM_TILE(tb2, tb1, kt + 2);
    }
    {   // tail tile 63: no stage, no end sync
        i32x4 af[4][2], bf[2][2];
#pragma unroll
        for (int n = 0; n < 2; ++n) { bf[n][0] = *(const i32x4*)(tb0 + boff[n][0]);
                                      bf[n][1] = *(const i32x4*)(tb0 + boff[n][1]); }
#pragma unroll
        for (int m = 0; m < 4; ++m) { af[m][0] = *(const i32x4*)(tb0 + aoff[m][0]);
                                      af[m][1] = *(const i32x4*)(tb0 + aoff[m][1]); }
#pragma unroll
        for (int kk = 0; kk < 2; ++kk)
#pragma unroll
        for (int m = 0; m < 4; ++m)
#pragma unroll
        for (int n = 0; n < 2; ++n)
            acc[m][n] = __builtin_amdgcn_mfma_i32_32x32x32_i8(
                af[m][kk], bf[n][kk], acc[m][n], 0, 0, 0);
    }

#undef STAGE4
#undef GEMM_TILE

    // Epilogue: 32x32 C/D layout col = lane&31, row = (q&3)+8*(q>>2)+4*(l>>5)
#pragma unroll
    for (int n = 0; n < 2; ++n) {
        int gc = bcol + wcN + n * 32 + r32;
        float ds = dsp[gc];
        int qb = qbp[gc];
#pragma unroll
        for (int m = 0; m < 4; ++m) {
            int grb = brow + wrM + m * 32 + 4 * kh;
#pragma unroll
            for (int q = 0; q < 16; ++q) {
                int gr = grb + (q & 3) + 8 * (q >> 2);
                C[(long)gr * N_DIM + gc] = (float)(acc[m][n][q] + qb) * ds;
            }
        }
    }
}

// ---------------------------------------------------------------------------
extern "C" void kernel_launch(void* const* d_in, const int* in_sizes, int n_in,
                              void* d_out, int out_size, void* d_ws, size_t ws_size,
                              hipStream_t stream)
{
    (void)in_sizes; (void)n_in; (void)out_size; (void)ws_size;
    const float* x   = (const float*)d_in[0];
    const int*   w   = (const int*)d_in[1];
    const float* is  = (const float*)d_in[2];
    const int*   io  = (const int*)d_in[3];
    const float* dq  = (const float*)d_in[4];
    const int*   qb  = (const int*)d_in[5];
    const int*   idx = (const int*)d_in[6];
    float* out = (float*)d_out;

    int8_t* xq  = (int8_t*)d_ws;                           // 33554432 B
    int8_t* bp  = xq + (size_t)M_DIM * K_DIM;              // 16777216 B
    float*  dsp = (float*)(bp + (size_t)N_DIM * K_DIM);    // 16384 B
    int*    qbp = (int*)(dsp + N_DIM);                     // 16384 B

    long quant_blocks = ((long)M_DIM * K_DIM) / 16 / 256;  // 8192
    quant_x_kernel<<<(int)quant_blocks, 256, 0, stream>>>(x, is, io, xq);
    pack_w_kernel<<<N_DIM, 256, 0, stream>>>(w, idx, dq, qb, bp, dsp, qbp);
    gemm_i8_kernel<<<(M_DIM / BM) * (N_DIM / BN), 512, 0, stream>>>(xq, bp, dsp, qbp, out);
}